// Round 21
// baseline (163.014 us; speedup 1.0000x reference)
//
#include <hip/hip_runtime.h>

// Problem constants (B,T,C,H,Dh) = (4,2048,1024,16,64); M = B*T = 8192.
#define SEQ_T 2048
#define NBATCH 4
#define CDIM 1024
#define NHEAD 16
#define MROWS 8192      // NBATCH * SEQ_T
#define QKVC 3072       // 3*CDIM

typedef unsigned short u16;
typedef __bf16 bf16x8 __attribute__((ext_vector_type(8)));
typedef float f32x4 __attribute__((ext_vector_type(4)));
typedef float f32x16 __attribute__((ext_vector_type(16)));
typedef unsigned short u16x8 __attribute__((ext_vector_type(8)));
typedef unsigned uint32x4 __attribute__((ext_vector_type(4)));

__device__ __forceinline__ u16 f32_to_bf16(float f) {
  union { float f; unsigned int u; } v; v.f = f;
  unsigned int u = v.u;
  unsigned int r = ((u >> 16) & 1u) + 0x7fffu;   // round-to-nearest-even
  return (u16)((u + r) >> 16);
}

__device__ __forceinline__ void gload_lds16(const u16* g, u16* l) {
  __builtin_amdgcn_global_load_lds(
      (const __attribute__((address_space(1))) void*)g,
      (__attribute__((address_space(3))) void*)l, 16, 0, 0);
}

// Blocked (MFMA-fragment-ordered) layout over a [R rows][K=1024] bf16 matrix
// (16x16x32-operand convention, used by the GEMM inputs):
// tile (row>>4, k>>5) is 1KB at ((row>>4)*32 + (k>>5))*512; lane = (row&15) +
// (((k>>3)&3)<<4) holds 8 u16 at j = k&7.

// -------------------------------------------- cast f32 -> blocked bf16 (for Xb)
__global__ __launch_bounds__(256) void cast_block_kernel(const float* __restrict__ in,
                                                         u16* __restrict__ out) {
  const int i = blockIdx.x * 256 + threadIdx.x;   // over MROWS*CDIM/8
  const int kg = i & 127;
  const int row = i >> 7;
  const float4 v0 = ((const float4*)in)[i * 2];
  const float4 v1 = ((const float4*)in)[i * 2 + 1];
  union { u16 u[8]; bf16x8 b; } o;
  o.u[0] = f32_to_bf16(v0.x); o.u[1] = f32_to_bf16(v0.y);
  o.u[2] = f32_to_bf16(v0.z); o.u[3] = f32_to_bf16(v0.w);
  o.u[4] = f32_to_bf16(v1.x); o.u[5] = f32_to_bf16(v1.y);
  o.u[6] = f32_to_bf16(v1.z); o.u[7] = f32_to_bf16(v1.w);
  const int tile = (row >> 4) * 32 + (kg >> 2);
  const int lane = (row & 15) + ((kg & 3) << 4);
  *(bf16x8*)(out + (size_t)tile * 512 + lane * 8) = o.b;
}

// --------- transpose + cast W [1024][Cc] -> blocked [Cc rows][1024 k]
__global__ void transpose_cast_block_kernel(const float* __restrict__ in,
                                            u16* __restrict__ out, int Cc) {
  __shared__ float tile[32][33];
  const int c0 = blockIdx.x * 32, r0 = blockIdx.y * 32;
  const int tx = threadIdx.x, ty = threadIdx.y;           // 32 x 8
  #pragma unroll
  for (int i = 0; i < 32; i += 8)
    tile[ty + i][tx] = in[(size_t)(r0 + ty + i) * Cc + c0 + tx];
  __syncthreads();
  const int t = ty * 32 + tx;
  if (t < 128) {
    const int cc = t & 31, kgq = t >> 5;
    union { u16 u[8]; bf16x8 b; } o;
    #pragma unroll
    for (int j = 0; j < 8; ++j) o.u[j] = f32_to_bf16(tile[kgq * 8 + j][cc]);
    const int rowN = c0 + cc;
    const int tileI = (rowN >> 4) * 32 + (r0 >> 5);
    const int lane = (rowN & 15) + (kgq << 4);
    *(bf16x8*)(out + (size_t)tileI * 512 + lane * 8) = o.b;
  }
}

// ---------------- GEMM1: 128x128 3-slot pipeline, BLOCKED inputs, fused epilogue.
// K/V scatter targets the 32x32-operand chunk layout (round-20, verified).
__global__ __launch_bounds__(256, 3)
void gemm1_kernel(const u16* __restrict__ Ab, const u16* __restrict__ Bb,
                  u16* __restrict__ Qb, u16* __restrict__ Kc, u16* __restrict__ Vc) {
  __shared__ u16 lds[24576];            // 48KB
  const int tid = threadIdx.x;
  const int lane = tid & 63, w = tid >> 6;
  const int wm = w >> 1, wn = w & 1;
  const int l15 = lane & 15, lhi = lane >> 4;
  const int row0 = blockIdx.x * 128, col0 = blockIdx.y * 128;
  const int rt0 = row0 >> 4, ct0 = col0 >> 4;

  const u16* aT = Ab + (size_t)(rt0 + w * 2) * 16384 + lane * 8;
  const u16* bT = Bb + (size_t)(ct0 + w * 2) * 16384 + lane * 8;

  f32x4 acc[4][4] = {};

#define SA(S) (lds + (S) * 4096)
#define SB(S) (lds + 12288 + (S) * 4096)
#define STAGE(KT, S)                                                            \
  {                                                                             \
    gload_lds16(aT + (size_t)(KT) * 512,         SA(S) + (w * 2) * 512);        \
    gload_lds16(aT + 16384 + (size_t)(KT) * 512, SA(S) + (w * 2 + 1) * 512);    \
    gload_lds16(bT + (size_t)(KT) * 512,         SB(S) + (w * 2) * 512);        \
    gload_lds16(bT + 16384 + (size_t)(KT) * 512, SB(S) + (w * 2 + 1) * 512);    \
  }
#define COMPUTE(S)                                                              \
  {                                                                             \
    bf16x8 af[4], bf[4];                                                        \
    _Pragma("unroll") for (int mi = 0; mi < 4; ++mi)                            \
      af[mi] = *(const bf16x8*)(SA(S) + (wm * 4 + mi) * 512 + lane * 8);        \
    _Pragma("unroll") for (int ni = 0; ni < 4; ++ni)                            \
      bf[ni] = *(const bf16x8*)(SB(S) + (wn * 4 + ni) * 512 + lane * 8);        \
    __builtin_amdgcn_s_setprio(1);                                              \
    _Pragma("unroll") for (int mi = 0; mi < 4; ++mi)                            \
      _Pragma("unroll") for (int ni = 0; ni < 4; ++ni)                          \
        acc[mi][ni] = __builtin_amdgcn_mfma_f32_16x16x32_bf16(af[mi], bf[ni],   \
                                                              acc[mi][ni], 0, 0, 0); \
    __builtin_amdgcn_s_setprio(0);                                              \
  }
#define WAITBAR4                                                                \
  asm volatile("s_waitcnt vmcnt(4)" ::: "memory");                              \
  __builtin_amdgcn_sched_barrier(0);                                            \
  __builtin_amdgcn_s_barrier();

  STAGE(0, 0);
  STAGE(1, 1);
  WAITBAR4;

  #pragma unroll 1
  for (int kt = 0; kt < 30; kt += 3) {
    STAGE(kt + 2, 2); COMPUTE(0); WAITBAR4;
    STAGE(kt + 3, 0); COMPUTE(1); WAITBAR4;
    STAGE(kt + 4, 1); COMPUTE(2); WAITBAR4;
  }
  COMPUTE(0);
  asm volatile("s_waitcnt vmcnt(0)" ::: "memory");
  __builtin_amdgcn_sched_barrier(0);
  __builtin_amdgcn_s_barrier();
  COMPUTE(1);
#undef STAGE
#undef COMPUTE
#undef WAITBAR4
#undef SA
#undef SB

  const int region = col0 >> 10;         // 0=Q, 1=K, 2=V (block-uniform)
  if (region == 0) {
    #pragma unroll
    for (int mt = 0; mt < 4; ++mt)
      #pragma unroll
      for (int nt = 0; nt < 4; ++nt)
        #pragma unroll
        for (int r = 0; r < 4; ++r) {
          const int rr = row0 + wm * 64 + mt * 16 + lhi * 4 + r;
          const int cc = col0 + wn * 64 + nt * 16 + l15;
          Qb[(size_t)rr * CDIM + cc] = f32_to_bf16(acc[mt][nt][r] * 0.18033688011f);
        }
  } else {
    __syncthreads();
    if (region == 1) {
      #pragma unroll
      for (int mt = 0; mt < 4; ++mt)
        #pragma unroll
        for (int nt = 0; nt < 4; ++nt)
          #pragma unroll
          for (int r = 0; r < 4; ++r) {
            const int sidx = wn * 8192 + (wm * 2 + (mt >> 1)) * 2048
                           + nt * 512
                           + ((mt & 1) * 16 + lhi * 4 + r + ((l15 >> 3) & 1) * 32) * 8
                           + (l15 & 7);
            lds[sidx] = f32_to_bf16(acc[mt][nt][r]);
          }
    } else {
      #pragma unroll
      for (int mt = 0; mt < 4; ++mt)
        #pragma unroll
        for (int nt = 0; nt < 4; ++nt)
          #pragma unroll
          for (int r = 0; r < 4; ++r) {
            const int sidx = wn * 8192 + (wm * 2 + (mt >> 1)) * 2048
                           + ((mt & 1) * 2 + (nt >> 1)) * 512
                           + ((nt & 1) * 16 + l15 + 32 * (lhi >> 1)) * 8
                           + (lhi & 1) * 4 + r;
            lds[sidx] = f32_to_bf16(acc[mt][nt][r]);
          }
    }
    __syncthreads();
    u16* dstB = (region == 1) ? Kc : Vc;
    const int bb = row0 >> 11;
    const int kv0b = (row0 & 2047) >> 5;
    const int hbase = (col0 & 1023) >> 6;
    #pragma unroll
    for (int hh = 0; hh < 2; ++hh) {
      u16* dst = dstB + (size_t)(bb * 16 + hbase + hh) * 131072 + (size_t)kv0b * 2048;
      const u16* src = lds + hh * 8192;
      #pragma unroll
      for (int c = 0; c < 4; ++c) {
        const int o = (c * 256 + tid) * 8;
        *(uint32x4*)(dst + o) = *(const uint32x4*)(src + o);
      }
    }
  }
}

// ---------------- GEMM2: 128x128 3-slot pipeline, BLOCKED inputs, f32 output
__global__ __launch_bounds__(256, 3)
void gemm2_kernel(const u16* __restrict__ Ab, const u16* __restrict__ Bb,
                  float* __restrict__ C) {
  __shared__ u16 lds[24576];
  const int tid = threadIdx.x;
  const int lane = tid & 63, w = tid >> 6;
  const int wm = w >> 1, wn = w & 1;
  const int l15 = lane & 15, lhi = lane >> 4;
  const int row0 = blockIdx.x * 128, col0 = blockIdx.y * 128;
  const int rt0 = row0 >> 4, ct0 = col0 >> 4;

  const u16* aT = Ab + (size_t)(rt0 + w * 2) * 16384 + lane * 8;
  const u16* bT = Bb + (size_t)(ct0 + w * 2) * 16384 + lane * 8;

  f32x4 acc[4][4] = {};

#define SA(S) (lds + (S) * 4096)
#define SB(S) (lds + 12288 + (S) * 4096)
#define STAGE(KT, S)                                                            \
  {                                                                             \
    gload_lds16(aT + (size_t)(KT) * 512,         SA(S) + (w * 2) * 512);        \
    gload_lds16(aT + 16384 + (size_t)(KT) * 512, SA(S) + (w * 2 + 1) * 512);    \
    gload_lds16(bT + (size_t)(KT) * 512,         SB(S) + (w * 2) * 512);        \
    gload_lds16(bT + 16384 + (size_t)(KT) * 512, SB(S) + (w * 2 + 1) * 512);    \
  }
#define COMPUTE(S)                                                              \
  {                                                                             \
    bf16x8 af[4], bf[4];                                                        \
    _Pragma("unroll") for (int mi = 0; mi < 4; ++mi)                            \
      af[mi] = *(const bf16x8*)(SA(S) + (wm * 4 + mi) * 512 + lane * 8);        \
    _Pragma("unroll") for (int ni = 0; ni < 4; ++ni)                            \
      bf[ni] = *(const bf16x8*)(SB(S) + (wn * 4 + ni) * 512 + lane * 8);        \
    __builtin_amdgcn_s_setprio(1);                                              \
    _Pragma("unroll") for (int mi = 0; mi < 4; ++mi)                            \
      _Pragma("unroll") for (int ni = 0; ni < 4; ++ni)                          \
        acc[mi][ni] = __builtin_amdgcn_mfma_f32_16x16x32_bf16(af[mi], bf[ni],   \
                                                              acc[mi][ni], 0, 0, 0); \
    __builtin_amdgcn_s_setprio(0);                                              \
  }
#define WAITBAR4                                                                \
  asm volatile("s_waitcnt vmcnt(4)" ::: "memory");                              \
  __builtin_amdgcn_sched_barrier(0);                                            \
  __builtin_amdgcn_s_barrier();

  STAGE(0, 0);
  STAGE(1, 1);
  WAITBAR4;

  #pragma unroll 1
  for (int kt = 0; kt < 30; kt += 3) {
    STAGE(kt + 2, 2); COMPUTE(0); WAITBAR4;
    STAGE(kt + 3, 0); COMPUTE(1); WAITBAR4;
    STAGE(kt + 4, 1); COMPUTE(2); WAITBAR4;
  }
  COMPUTE(0);
  asm volatile("s_waitcnt vmcnt(0)" ::: "memory");
  __builtin_amdgcn_sched_barrier(0);
  __builtin_amdgcn_s_barrier();
  COMPUTE(1);
#undef STAGE
#undef COMPUTE
#undef WAITBAR4
#undef SA
#undef SB

  #pragma unroll
  for (int mt = 0; mt < 4; ++mt)
    #pragma unroll
    for (int nt = 0; nt < 4; ++nt)
      #pragma unroll
      for (int r = 0; r < 4; ++r) {
        const int rr = row0 + wm * 64 + mt * 16 + lhi * 4 + r;
        const int cc = col0 + wn * 64 + nt * 16 + l15;
        C[(size_t)rr * CDIM + cc] = acc[mt][nt][r];
      }
}

// ---------------------------------------------------------------- flash attention
// Round-21: 32x32 MFMA, UN-PAIRED (one 32-q job per wave) -> grid 1024,
// launch_bounds(256,4): restores 4 blocks/CU occupancy while keeping the
// 32x32 issue savings (round 20: VALU 55->43.7 but occupancy halved).
// Block g handles jobs {2g, 2g+1, 63-2g, 62-2g} (per-block work g-independent).
template <bool DOMASK>
__device__ __forceinline__ void attn_step32(const bf16x8 (&qf)[4],
                                            const bf16x8 (&kf)[4],
                                            const bf16x8 (&vb)[2][2],
                                            const bf16x8 ones,
                                            f32x16 (&acc)[2], f32x16& acc1,
                                            int l31, int lhi5, int kv0, int qg) {
  f32x16 st = {};
  #pragma unroll
  for (int i = 0; i < 4; ++i)
    st = __builtin_amdgcn_mfma_f32_32x32x16_bf16(kf[i], qf[i], st, 0, 0, 0);
  #pragma unroll
  for (int g = 0; g < 16; ++g) {
    float sv = st[g];
    if (DOMASK) {
      const int kvg = kv0 + (g & 3) + 8 * (g >> 2) + 4 * lhi5;
      sv = (kvg > qg) ? -__builtin_inff() : sv;
    }
    st[g] = exp2f(sv);
  }
  unsigned c0, c1, c2, c3, c4, c5, c6, c7;
  asm("v_cvt_pk_bf16_f32 %0, %1, %2" : "=v"(c0) : "v"(st[0]),  "v"(st[1]));
  asm("v_cvt_pk_bf16_f32 %0, %1, %2" : "=v"(c1) : "v"(st[2]),  "v"(st[3]));
  asm("v_cvt_pk_bf16_f32 %0, %1, %2" : "=v"(c2) : "v"(st[4]),  "v"(st[5]));
  asm("v_cvt_pk_bf16_f32 %0, %1, %2" : "=v"(c3) : "v"(st[6]),  "v"(st[7]));
  asm("v_cvt_pk_bf16_f32 %0, %1, %2" : "=v"(c4) : "v"(st[8]),  "v"(st[9]));
  asm("v_cvt_pk_bf16_f32 %0, %1, %2" : "=v"(c5) : "v"(st[10]), "v"(st[11]));
  asm("v_cvt_pk_bf16_f32 %0, %1, %2" : "=v"(c6) : "v"(st[12]), "v"(st[13]));
  asm("v_cvt_pk_bf16_f32 %0, %1, %2" : "=v"(c7) : "v"(st[14]), "v"(st[15]));
  asm("v_permlane32_swap_b32 %0, %1" : "+v"(c0), "+v"(c2));
  asm("v_permlane32_swap_b32 %0, %1" : "+v"(c1), "+v"(c3));
  asm("v_permlane32_swap_b32 %0, %1" : "+v"(c4), "+v"(c6));
  asm("v_permlane32_swap_b32 %0, %1" : "+v"(c5), "+v"(c7));
  uint32x4 p0w, p1w;
  p0w[0] = c0; p0w[1] = c1; p0w[2] = c2; p0w[3] = c3;
  p1w[0] = c4; p1w[1] = c5; p1w[2] = c6; p1w[3] = c7;
  const bf16x8 pa0 = __builtin_bit_cast(bf16x8, p0w);
  const bf16x8 pa1 = __builtin_bit_cast(bf16x8, p1w);
  acc[0] = __builtin_amdgcn_mfma_f32_32x32x16_bf16(pa0, vb[0][0], acc[0], 0, 0, 0);
  acc[0] = __builtin_amdgcn_mfma_f32_32x32x16_bf16(pa1, vb[1][0], acc[0], 0, 0, 0);
  acc[1] = __builtin_amdgcn_mfma_f32_32x32x16_bf16(pa0, vb[0][1], acc[1], 0, 0, 0);
  acc[1] = __builtin_amdgcn_mfma_f32_32x32x16_bf16(pa1, vb[1][1], acc[1], 0, 0, 0);
  acc1 = __builtin_amdgcn_mfma_f32_32x32x16_bf16(pa0, ones, acc1, 0, 0, 0);
  acc1 = __builtin_amdgcn_mfma_f32_32x32x16_bf16(pa1, ones, acc1, 0, 0, 0);
}

__global__ __launch_bounds__(256, 4) void attn_kernel(const u16* __restrict__ Qb,
                                                      const u16* __restrict__ Kc,
                                                      const u16* __restrict__ Vc,
                                                      u16* __restrict__ Yb) {
  __shared__ u16 Kl[2][4096];     // [buf][2 chunks x 2048 u16] = 8KB each
  __shared__ u16 Vl[2][4096];
  const int tid = threadIdx.x, lane = tid & 63, wid = tid >> 6;
  const int l31 = lane & 31, lhi5 = lane >> 5;
  // decode: id = xcd + 8*g + 128*hi3, g = 0..15; bh = hi3*8 + xcd.
  const int id = blockIdx.x;
  const int xcd = id & 7, g = (id >> 3) & 15, hi3 = id >> 7;
  const int bh = hi3 * 8 + xcd;
  const int b = bh >> 4, h = bh & 15;
  // one 32-q job per wave: {2g, 2g+1, 63-2g, 62-2g}
  const int jw = (wid == 0) ? 2 * g : (wid == 1) ? 2 * g + 1
               : (wid == 2) ? 63 - 2 * g : 62 - 2 * g;
  const int q0 = jw * 32;
  const int nch = jw + 1;                        // 32-kv chunks this job needs
  const int nc2max = 32 - g;                     // block-uniform 64-kv iterations
  const u16* Qp  = Qb + (size_t)b * SEQ_T * CDIM + h * 64;
  const u16* KcC = Kc + (size_t)bh * 131072;
  const u16* VcC = Vc + (size_t)bh * 131072;

  u16x8 ou;
  #pragma unroll
  for (int j = 0; j < 8; ++j) ou[j] = 0x3F80;
  const bf16x8 ones = __builtin_bit_cast(bf16x8, ou);

  // stage chunk pair 0 (each wave: 2KB of K + 2KB of V)
  gload_lds16(KcC + wid * 512 + lane * 8,        &Kl[0][wid * 512]);
  gload_lds16(KcC + 2048 + wid * 512 + lane * 8, &Kl[0][2048 + wid * 512]);
  gload_lds16(VcC + wid * 512 + lane * 8,        &Vl[0][wid * 512]);
  gload_lds16(VcC + 2048 + wid * 512 + lane * 8, &Vl[0][2048 + wid * 512]);

  // Q B-frags: qf[i] lane l = Q[q0 + (l&31)][16i + (l>>5)*8 + j]
  bf16x8 qf[4];
  #pragma unroll
  for (int i = 0; i < 4; ++i)
    qf[i] = *(const bf16x8*)(Qp + (size_t)(q0 + l31) * CDIM + i * 16 + lhi5 * 8);
  const int qg = q0 + l31;

  f32x16 acc[2] = {};
  f32x16 acc1 = {};

  __syncthreads();

  int cbuf = 0;
  for (int ic2 = 0; ic2 < nc2max; ++ic2) {
    if (ic2 + 1 < nc2max) {
      const u16* kg = KcC + (size_t)(ic2 + 1) * 4096 + wid * 512 + lane * 8;
      const u16* vg = VcC + (size_t)(ic2 + 1) * 4096 + wid * 512 + lane * 8;
      gload_lds16(kg,        &Kl[cbuf ^ 1][wid * 512]);
      gload_lds16(kg + 2048, &Kl[cbuf ^ 1][2048 + wid * 512]);
      gload_lds16(vg,        &Vl[cbuf ^ 1][wid * 512]);
      gload_lds16(vg + 2048, &Vl[cbuf ^ 1][2048 + wid * 512]);
    }
    #pragma unroll
    for (int h2 = 0; h2 < 2; ++h2) {
      const int c = ic2 * 2 + h2;
      if (c < nch) {
        const u16* kb = &Kl[cbuf][h2 * 2048];
        const u16* vp = &Vl[cbuf][h2 * 2048];
        bf16x8 kf[4], vb[2][2];
        #pragma unroll
        for (int i = 0; i < 4; ++i)
          kf[i] = *(const bf16x8*)(kb + i * 512 + lane * 8);
        #pragma unroll
        for (int kk = 0; kk < 2; ++kk)
          #pragma unroll
          for (int dh = 0; dh < 2; ++dh)
            vb[kk][dh] = *(const bf16x8*)(vp + (kk * 2 + dh) * 512 + lane * 8);

        const int kv0 = c * 32;
        if (c == nch - 1)
          attn_step32<true>(qf, kf, vb, ones, acc, acc1, l31, lhi5, kv0, qg);
        else
          attn_step32<false>(qf, kf, vb, ones, acc, acc1, l31, lhi5, kv0, qg);
      }
    }
    __syncthreads();
    cbuf ^= 1;
  }

  // epilogue: acc1[g] = rowsum(q(g,lane)); write Yb in GEMM blocked layout.
  #pragma unroll
  for (int g2 = 0; g2 < 16; ++g2) {
    const int ql = (g2 & 3) + 8 * (g2 >> 2) + 4 * lhi5;
    const float iv = 1.0f / acc1[g2];
    const int laneb = (ql & 15) + ((l31 >> 3) << 4);
    const int jj = l31 & 7;
    const size_t rr = (size_t)b * 2048 + q0 + ql;
    #pragma unroll
    for (int dh = 0; dh < 2; ++dh)
      Yb[((rr >> 4) * 32 + h * 2 + dh) * 512 + laneb * 8 + jj] =
          f32_to_bf16(acc[dh][g2] * iv);
  }
}

// ---------------------------------------------------------------- launch
extern "C" void kernel_launch(void* const* d_in, const int* in_sizes, int n_in,
                              void* d_out, int out_size, void* d_ws, size_t ws_size,
                              hipStream_t stream) {
  const float* x      = (const float*)d_in[0];
  const float* w_qkv  = (const float*)d_in[1];
  const float* w_proj = (const float*)d_in[2];
  float* out = (float*)d_out;

  u16* Xb  = (u16*)d_ws;                                // blocked x
  u16* Wqt = Xb  + (size_t)MROWS * CDIM;                // blocked w_qkv^T
  u16* Wpt = Wqt + (size_t)QKVC * CDIM;                 // blocked w_proj^T
  u16* Qb  = Wpt + (size_t)CDIM * CDIM;                 // 8192*1024 (Q, pre-scaled)
  u16* Kc  = Qb  + (size_t)MROWS * CDIM;                // 64*131072 chunked K (32x32)
  u16* Vc  = Kc  + (size_t)64 * 131072;                 // 64*131072 chunked V (32x32)
  u16* Yb  = Vc  + (size_t)64 * 131072;                 // 8192*1024 blocked

  // casts / transposes (all blocked)
  cast_block_kernel<<<MROWS * CDIM / 8 / 256, 256, 0, stream>>>(x, Xb);
  transpose_cast_block_kernel<<<dim3(QKVC / 32, CDIM / 32), dim3(32, 8), 0, stream>>>(w_qkv, Wqt, QKVC);
  transpose_cast_block_kernel<<<dim3(CDIM / 32, CDIM / 32), dim3(32, 8), 0, stream>>>(w_proj, Wpt, CDIM);

  // qkv projection: blocked inputs, fused epilogue (Q->Qb scaled, K->Kc, V->Vc)
  gemm1_kernel<<<dim3(MROWS / 128, QKVC / 128), 256, 0, stream>>>(Xb, Wqt, Qb, Kc, Vc);

  // attention (32x32 MFMA, un-paired 32-q jobs, grid 1024, 4 blocks/CU)
  attn_kernel<<<1024, 256, 0, stream>>>(Qb, Kc, Vc, Yb);

  // out = y @ w_proj  (blocked inputs, f32 out)
  gemm2_kernel<<<dim3(MROWS / 128, CDIM / 128), 256, 0, stream>>>(Yb, Wpt, out);
}

// Round 22
// 156.235 us; speedup vs baseline: 1.0434x; 1.0434x over previous
//
#include <hip/hip_runtime.h>

// Problem constants (B,T,C,H,Dh) = (4,2048,1024,16,64); M = B*T = 8192.
#define SEQ_T 2048
#define NBATCH 4
#define CDIM 1024
#define NHEAD 16
#define MROWS 8192      // NBATCH * SEQ_T
#define QKVC 3072       // 3*CDIM

typedef unsigned short u16;
typedef __bf16 bf16x8 __attribute__((ext_vector_type(8)));
typedef float f32x4 __attribute__((ext_vector_type(4)));
typedef unsigned short u16x8 __attribute__((ext_vector_type(8)));
typedef unsigned uint32x4 __attribute__((ext_vector_type(4)));

__device__ __forceinline__ u16 f32_to_bf16(float f) {
  union { float f; unsigned int u; } v; v.f = f;
  unsigned int u = v.u;
  unsigned int r = ((u >> 16) & 1u) + 0x7fffu;   // round-to-nearest-even
  return (u16)((u + r) >> 16);
}

__device__ __forceinline__ void gload_lds16(const u16* g, u16* l) {
  __builtin_amdgcn_global_load_lds(
      (const __attribute__((address_space(1))) void*)g,
      (__attribute__((address_space(3))) void*)l, 16, 0, 0);
}

// Blocked (MFMA-fragment-ordered) layout over a [R rows][K=1024] bf16 matrix:
// tile (row>>4, k>>5) is 1KB contiguous at index ((row>>4)*32 + (k>>5))*512;
// within, lane = (row&15) + (((k>>3)&3)<<4) holds 8 u16 at j = k&7.

// -------------------------------------------- cast f32 -> blocked bf16 (for Xb)
__global__ __launch_bounds__(256) void cast_block_kernel(const float* __restrict__ in,
                                                         u16* __restrict__ out) {
  const int i = blockIdx.x * 256 + threadIdx.x;   // over MROWS*CDIM/8
  const int kg = i & 127;                         // k-group of 8 (CDIM/8=128)
  const int row = i >> 7;
  const float4 v0 = ((const float4*)in)[i * 2];
  const float4 v1 = ((const float4*)in)[i * 2 + 1];
  union { u16 u[8]; bf16x8 b; } o;
  o.u[0] = f32_to_bf16(v0.x); o.u[1] = f32_to_bf16(v0.y);
  o.u[2] = f32_to_bf16(v0.z); o.u[3] = f32_to_bf16(v0.w);
  o.u[4] = f32_to_bf16(v1.x); o.u[5] = f32_to_bf16(v1.y);
  o.u[6] = f32_to_bf16(v1.z); o.u[7] = f32_to_bf16(v1.w);
  const int tile = (row >> 4) * 32 + (kg >> 2);
  const int lane = (row & 15) + ((kg & 3) << 4);
  *(bf16x8*)(out + (size_t)tile * 512 + lane * 8) = o.b;
}

// --------- transpose + cast W [1024][Cc] -> blocked [Cc rows][1024 k]
__global__ void transpose_cast_block_kernel(const float* __restrict__ in,
                                            u16* __restrict__ out, int Cc) {
  __shared__ float tile[32][33];
  const int c0 = blockIdx.x * 32, r0 = blockIdx.y * 32;
  const int tx = threadIdx.x, ty = threadIdx.y;           // 32 x 8
  #pragma unroll
  for (int i = 0; i < 32; i += 8)
    tile[ty + i][tx] = in[(size_t)(r0 + ty + i) * Cc + c0 + tx];
  __syncthreads();
  const int t = ty * 32 + tx;
  if (t < 128) {
    const int cc = t & 31, kgq = t >> 5;
    union { u16 u[8]; bf16x8 b; } o;
    #pragma unroll
    for (int j = 0; j < 8; ++j) o.u[j] = f32_to_bf16(tile[kgq * 8 + j][cc]);
    const int rowN = c0 + cc;
    const int tileI = (rowN >> 4) * 32 + (r0 >> 5);
    const int lane = (rowN & 15) + (kgq << 4);
    *(bf16x8*)(out + (size_t)tileI * 512 + lane * 8) = o.b;
  }
}

// ---------------- GEMM1: 128x128 3-slot pipeline, BLOCKED inputs, fused epilogue
// (round-19 verified: Q->Qb scaled; K/V -> 16x16 lane-linear fragment tiles via
// LDS scratch + coalesced copy-out)
__global__ __launch_bounds__(256, 3)
void gemm1_kernel(const u16* __restrict__ Ab, const u16* __restrict__ Bb,
                  u16* __restrict__ Qb, u16* __restrict__ Kc, u16* __restrict__ Vc) {
  __shared__ u16 lds[24576];            // 48KB
  const int tid = threadIdx.x;
  const int lane = tid & 63, w = tid >> 6;
  const int wm = w >> 1, wn = w & 1;
  const int l15 = lane & 15, lhi = lane >> 4;
  const int row0 = blockIdx.x * 128, col0 = blockIdx.y * 128;
  const int rt0 = row0 >> 4, ct0 = col0 >> 4;

  const u16* aT = Ab + (size_t)(rt0 + w * 2) * 16384 + lane * 8;
  const u16* bT = Bb + (size_t)(ct0 + w * 2) * 16384 + lane * 8;

  f32x4 acc[4][4] = {};

#define SA(S) (lds + (S) * 4096)
#define SB(S) (lds + 12288 + (S) * 4096)
#define STAGE(KT, S)                                                            \
  {                                                                             \
    gload_lds16(aT + (size_t)(KT) * 512,         SA(S) + (w * 2) * 512);        \
    gload_lds16(aT + 16384 + (size_t)(KT) * 512, SA(S) + (w * 2 + 1) * 512);    \
    gload_lds16(bT + (size_t)(KT) * 512,         SB(S) + (w * 2) * 512);        \
    gload_lds16(bT + 16384 + (size_t)(KT) * 512, SB(S) + (w * 2 + 1) * 512);    \
  }
#define COMPUTE(S)                                                              \
  {                                                                             \
    bf16x8 af[4], bf[4];                                                        \
    _Pragma("unroll") for (int mi = 0; mi < 4; ++mi)                            \
      af[mi] = *(const bf16x8*)(SA(S) + (wm * 4 + mi) * 512 + lane * 8);        \
    _Pragma("unroll") for (int ni = 0; ni < 4; ++ni)                            \
      bf[ni] = *(const bf16x8*)(SB(S) + (wn * 4 + ni) * 512 + lane * 8);        \
    __builtin_amdgcn_s_setprio(1);                                              \
    _Pragma("unroll") for (int mi = 0; mi < 4; ++mi)                            \
      _Pragma("unroll") for (int ni = 0; ni < 4; ++ni)                          \
        acc[mi][ni] = __builtin_amdgcn_mfma_f32_16x16x32_bf16(af[mi], bf[ni],   \
                                                              acc[mi][ni], 0, 0, 0); \
    __builtin_amdgcn_s_setprio(0);                                              \
  }
#define WAITBAR4                                                                \
  asm volatile("s_waitcnt vmcnt(4)" ::: "memory");                              \
  __builtin_amdgcn_sched_barrier(0);                                            \
  __builtin_amdgcn_s_barrier();

  STAGE(0, 0);
  STAGE(1, 1);
  WAITBAR4;

  #pragma unroll 1
  for (int kt = 0; kt < 30; kt += 3) {
    STAGE(kt + 2, 2); COMPUTE(0); WAITBAR4;
    STAGE(kt + 3, 0); COMPUTE(1); WAITBAR4;
    STAGE(kt + 4, 1); COMPUTE(2); WAITBAR4;
  }
  COMPUTE(0);
  asm volatile("s_waitcnt vmcnt(0)" ::: "memory");
  __builtin_amdgcn_sched_barrier(0);
  __builtin_amdgcn_s_barrier();
  COMPUTE(1);
#undef STAGE
#undef COMPUTE
#undef WAITBAR4
#undef SA
#undef SB

  const int region = col0 >> 10;         // 0=Q, 1=K, 2=V (block-uniform)
  if (region == 0) {
    #pragma unroll
    for (int mt = 0; mt < 4; ++mt)
      #pragma unroll
      for (int nt = 0; nt < 4; ++nt)
        #pragma unroll
        for (int r = 0; r < 4; ++r) {
          const int rr = row0 + wm * 64 + mt * 16 + lhi * 4 + r;
          const int cc = col0 + wn * 64 + nt * 16 + l15;
          Qb[(size_t)rr * CDIM + cc] = f32_to_bf16(acc[mt][nt][r] * 0.18033688011f);
        }
  } else {
    __syncthreads();
    if (region == 1) {
      #pragma unroll
      for (int mt = 0; mt < 4; ++mt)
        #pragma unroll
        for (int nt = 0; nt < 4; ++nt)
          #pragma unroll
          for (int r = 0; r < 4; ++r) {
            const int sidx = (wn * 4 + wm * 2 + (mt >> 1)) * 2048
                           + ((mt & 1) * 2 + (nt >> 1)) * 512
                           + ((nt & 1) * 2 + (l15 >> 3)) * 128
                           + (lhi * 4 + r) * 8 + (l15 & 7);
            lds[sidx] = f32_to_bf16(acc[mt][nt][r]);
          }
    } else {
      #pragma unroll
      for (int mt = 0; mt < 4; ++mt)
        #pragma unroll
        for (int nt = 0; nt < 4; ++nt)
          #pragma unroll
          for (int r = 0; r < 4; ++r) {
            const int sidx = (wn * 4 + wm * 2 + (mt >> 1)) * 2048
                           + nt * 512
                           + ((mt & 1) * 2 + (lhi >> 1)) * 128
                           + l15 * 8 + (lhi & 1) * 4 + r;
            lds[sidx] = f32_to_bf16(acc[mt][nt][r]);
          }
    }
    __syncthreads();
    u16* dstB = (region == 1) ? Kc : Vc;
    const int bb = row0 >> 11;
    const int kv0b = (row0 & 2047) >> 5;
    const int hbase = (col0 & 1023) >> 6;
    #pragma unroll
    for (int hh = 0; hh < 2; ++hh) {
      u16* dst = dstB + (size_t)(bb * 16 + hbase + hh) * 131072 + (size_t)kv0b * 2048;
      const u16* src = lds + hh * 8192;
      #pragma unroll
      for (int c = 0; c < 4; ++c) {
        const int o = (c * 256 + tid) * 8;
        *(uint32x4*)(dst + o) = *(const uint32x4*)(src + o);
      }
    }
  }
}

// ---------------- GEMM2: 128x128 3-slot pipeline, BLOCKED inputs, f32 output
__global__ __launch_bounds__(256, 3)
void gemm2_kernel(const u16* __restrict__ Ab, const u16* __restrict__ Bb,
                  float* __restrict__ C) {
  __shared__ u16 lds[24576];
  const int tid = threadIdx.x;
  const int lane = tid & 63, w = tid >> 6;
  const int wm = w >> 1, wn = w & 1;
  const int l15 = lane & 15, lhi = lane >> 4;
  const int row0 = blockIdx.x * 128, col0 = blockIdx.y * 128;
  const int rt0 = row0 >> 4, ct0 = col0 >> 4;

  const u16* aT = Ab + (size_t)(rt0 + w * 2) * 16384 + lane * 8;
  const u16* bT = Bb + (size_t)(ct0 + w * 2) * 16384 + lane * 8;

  f32x4 acc[4][4] = {};

#define SA(S) (lds + (S) * 4096)
#define SB(S) (lds + 12288 + (S) * 4096)
#define STAGE(KT, S)                                                            \
  {                                                                             \
    gload_lds16(aT + (size_t)(KT) * 512,         SA(S) + (w * 2) * 512);        \
    gload_lds16(aT + 16384 + (size_t)(KT) * 512, SA(S) + (w * 2 + 1) * 512);    \
    gload_lds16(bT + (size_t)(KT) * 512,         SB(S) + (w * 2) * 512);        \
    gload_lds16(bT + 16384 + (size_t)(KT) * 512, SB(S) + (w * 2 + 1) * 512);    \
  }
#define COMPUTE(S)                                                              \
  {                                                                             \
    bf16x8 af[4], bf[4];                                                        \
    _Pragma("unroll") for (int mi = 0; mi < 4; ++mi)                            \
      af[mi] = *(const bf16x8*)(SA(S) + (wm * 4 + mi) * 512 + lane * 8);        \
    _Pragma("unroll") for (int ni = 0; ni < 4; ++ni)                            \
      bf[ni] = *(const bf16x8*)(SB(S) + (wn * 4 + ni) * 512 + lane * 8);        \
    __builtin_amdgcn_s_setprio(1);                                              \
    _Pragma("unroll") for (int mi = 0; mi < 4; ++mi)                            \
      _Pragma("unroll") for (int ni = 0; ni < 4; ++ni)                          \
        acc[mi][ni] = __builtin_amdgcn_mfma_f32_16x16x32_bf16(af[mi], bf[ni],   \
                                                              acc[mi][ni], 0, 0, 0); \
    __builtin_amdgcn_s_setprio(0);                                              \
  }
#define WAITBAR4                                                                \
  asm volatile("s_waitcnt vmcnt(4)" ::: "memory");                              \
  __builtin_amdgcn_sched_barrier(0);                                            \
  __builtin_amdgcn_s_barrier();

  STAGE(0, 0);
  STAGE(1, 1);
  WAITBAR4;

  #pragma unroll 1
  for (int kt = 0; kt < 30; kt += 3) {
    STAGE(kt + 2, 2); COMPUTE(0); WAITBAR4;
    STAGE(kt + 3, 0); COMPUTE(1); WAITBAR4;
    STAGE(kt + 4, 1); COMPUTE(2); WAITBAR4;
  }
  COMPUTE(0);
  asm volatile("s_waitcnt vmcnt(0)" ::: "memory");
  __builtin_amdgcn_sched_barrier(0);
  __builtin_amdgcn_s_barrier();
  COMPUTE(1);
#undef STAGE
#undef COMPUTE
#undef WAITBAR4
#undef SA
#undef SB

  #pragma unroll
  for (int mt = 0; mt < 4; ++mt)
    #pragma unroll
    for (int nt = 0; nt < 4; ++nt)
      #pragma unroll
      for (int r = 0; r < 4; ++r) {
        const int rr = row0 + wm * 64 + mt * 16 + lhi * 4 + r;
        const int cc = col0 + wn * 64 + nt * 16 + l15;
        C[(size_t)rr * CDIM + cc] = acc[mt][nt][r];
      }
}

// ---------------------------------------------------------------- flash attention
// Round-22: round-19 checkpoint (16x16 paired, KVBLK=64, rowsum-MFMA, blocked
// Yb write) + T5 setprio around the MFMA clusters (4 waves/block at different
// causal phases -> scheduler has role diversity to arbitrate).
template <bool DOMASK>
__device__ __forceinline__ void attn_step(const bf16x8 (&qf)[2],
                                          const bf16x8 (&kf)[2][2],
                                          const bf16x8 (&vb)[4],
                                          const bf16x8 ones,
                                          f32x4 (&acc)[4], f32x4& acc1,
                                          int l15, int lhi, int kv0, int qg) {
  f32x4 st[2];
  __builtin_amdgcn_s_setprio(1);
  #pragma unroll
  for (int t = 0; t < 2; ++t) {
    f32x4 z = {0.f, 0.f, 0.f, 0.f};
    z = __builtin_amdgcn_mfma_f32_16x16x32_bf16(kf[t][0], qf[0], z, 0, 0, 0);
    z = __builtin_amdgcn_mfma_f32_16x16x32_bf16(kf[t][1], qf[1], z, 0, 0, 0);
    st[t] = z;
  }
  __builtin_amdgcn_s_setprio(0);
  #pragma unroll
  for (int t = 0; t < 2; ++t)
    #pragma unroll
    for (int r = 0; r < 4; ++r) {
      float sv = st[t][r];                       // Q pre-scaled: log2-domain score
      if (DOMASK) {
        const int kvg = kv0 + t * 16 + lhi * 4 + r;
        sv = (kvg > qg) ? -__builtin_inff() : sv;
      }
      st[t][r] = exp2f(sv);
    }
  unsigned c00, c01, c10, c11;
  asm("v_cvt_pk_bf16_f32 %0, %1, %2" : "=v"(c00) : "v"(st[0][0]), "v"(st[0][1]));
  asm("v_cvt_pk_bf16_f32 %0, %1, %2" : "=v"(c01) : "v"(st[0][2]), "v"(st[0][3]));
  asm("v_cvt_pk_bf16_f32 %0, %1, %2" : "=v"(c10) : "v"(st[1][0]), "v"(st[1][1]));
  asm("v_cvt_pk_bf16_f32 %0, %1, %2" : "=v"(c11) : "v"(st[1][2]), "v"(st[1][3]));
  asm("v_permlane32_swap_b32 %0, %1" : "+v"(c00), "+v"(c10));
  asm("v_permlane32_swap_b32 %0, %1" : "+v"(c01), "+v"(c11));
  asm("v_permlane16_swap_b32 %0, %1" : "+v"(c00), "+v"(c10));
  asm("v_permlane16_swap_b32 %0, %1" : "+v"(c01), "+v"(c11));
  uint32x4 pw; pw[0] = c00; pw[1] = c01; pw[2] = c10; pw[3] = c11;
  const bf16x8 pa = __builtin_bit_cast(bf16x8, pw);
  __builtin_amdgcn_s_setprio(1);
  #pragma unroll
  for (int d = 0; d < 4; ++d)
    acc[d] = __builtin_amdgcn_mfma_f32_16x16x32_bf16(pa, vb[d], acc[d], 0, 0, 0);
  acc1 = __builtin_amdgcn_mfma_f32_16x16x32_bf16(pa, ones, acc1, 0, 0, 0);
  __builtin_amdgcn_s_setprio(0);
}

__global__ __launch_bounds__(256, 4) void attn_kernel(const u16* __restrict__ Qb,
                                                      const u16* __restrict__ Kc,
                                                      const u16* __restrict__ Vc,
                                                      u16* __restrict__ Yb) {
  __shared__ u16 Kl[2][4096];     // [buf][2 chunks x 2048] = 8KB each
  __shared__ u16 Vl[2][4096];
  const int tid = threadIdx.x, lane = tid & 63, wid = tid >> 6;
  const int l15 = lane & 15, lhi = lane >> 4;
  const int id = blockIdx.x;
  const int xcd = id & 7, k = (id >> 3) & 15, hi3 = id >> 7;
  const int bh = hi3 * 8 + xcd;
  const int b = bh >> 4, h = bh & 15;
  const int pa = k * 4 + wid;
  const int qA0 = pa * 16, qB0 = (127 - pa) * 16;
  const int nchA = pa / 2 + 1, nchB = (127 - pa) / 2 + 1;
  const int nc2max = 32 - k;                     // = ncmax/2 (ncmax = 64-2k, even)
  const u16* Qp  = Qb + (size_t)b * SEQ_T * CDIM + h * 64;
  const u16* KcC = Kc + (size_t)bh * 131072;
  const u16* VcC = Vc + (size_t)bh * 131072;

  u16x8 ou;
  #pragma unroll
  for (int j = 0; j < 8; ++j) ou[j] = 0x3F80;
  const bf16x8 ones = __builtin_bit_cast(bf16x8, ou);

  // stage chunk pair 0 (each wave: 2KB of K + 2KB of V)
  gload_lds16(KcC + wid * 512 + lane * 8,        &Kl[0][wid * 512]);
  gload_lds16(KcC + 2048 + wid * 512 + lane * 8, &Kl[0][2048 + wid * 512]);
  gload_lds16(VcC + wid * 512 + lane * 8,        &Vl[0][wid * 512]);
  gload_lds16(VcC + 2048 + wid * 512 + lane * 8, &Vl[0][2048 + wid * 512]);

  bf16x8 qfA[2], qfB[2];
  #pragma unroll
  for (int i = 0; i < 2; ++i) {
    qfA[i] = *(const bf16x8*)(Qp + (size_t)(qA0 + l15) * CDIM + i * 32 + lhi * 8);
    qfB[i] = *(const bf16x8*)(Qp + (size_t)(qB0 + l15) * CDIM + i * 32 + lhi * 8);
  }
  const int qgA = qA0 + l15, qgB = qB0 + l15;

  f32x4 accA[4] = {}, accB[4] = {};
  f32x4 acc1A = {}, acc1B = {};

  __syncthreads();

  int cbuf = 0;
  for (int ic2 = 0; ic2 < nc2max; ++ic2) {
    if (ic2 + 1 < nc2max) {
      const u16* kg = KcC + (size_t)(ic2 + 1) * 4096 + wid * 512 + lane * 8;
      const u16* vg = VcC + (size_t)(ic2 + 1) * 4096 + wid * 512 + lane * 8;
      gload_lds16(kg,        &Kl[cbuf ^ 1][wid * 512]);
      gload_lds16(kg + 2048, &Kl[cbuf ^ 1][2048 + wid * 512]);
      gload_lds16(vg,        &Vl[cbuf ^ 1][wid * 512]);
      gload_lds16(vg + 2048, &Vl[cbuf ^ 1][2048 + wid * 512]);
    }
    #pragma unroll
    for (int h2 = 0; h2 < 2; ++h2) {
      const int c = ic2 * 2 + h2;
      const u16* kb = &Kl[cbuf][h2 * 2048];
      const u16* vp = &Vl[cbuf][h2 * 2048];
      bf16x8 kf[2][2], vb[4];
      #pragma unroll
      for (int t = 0; t < 2; ++t)
        #pragma unroll
        for (int i = 0; i < 2; ++i)
          kf[t][i] = *(const bf16x8*)(kb + (t * 2 + i) * 512 + lane * 8);
      #pragma unroll
      for (int d = 0; d < 4; ++d)
        vb[d] = *(const bf16x8*)(vp + d * 512 + lane * 8);

      const int kv0 = c * 32;
      if (c < nchB) {
        if (c == nchB - 1)
          attn_step<true>(qfB, kf, vb, ones, accB, acc1B, l15, lhi, kv0, qgB);
        else
          attn_step<false>(qfB, kf, vb, ones, accB, acc1B, l15, lhi, kv0, qgB);
      }
      if (c < nchA) {
        if (c == nchA - 1)
          attn_step<true>(qfA, kf, vb, ones, accA, acc1A, l15, lhi, kv0, qgA);
        else
          attn_step<false>(qfA, kf, vb, ones, accA, acc1A, l15, lhi, kv0, qgA);
      }
    }
    __syncthreads();
    cbuf ^= 1;
  }

  // epilogue: rowsum in acc1[r]; write Yb in BLOCKED layout
  #pragma unroll
  for (int r = 0; r < 4; ++r) {
    const float ivA = 1.0f / acc1A[r];
    const float ivB = 1.0f / acc1B[r];
    const int rl = lhi * 4 + r;                  // rr & 15
    #pragma unroll
    for (int d = 0; d < 4; ++d) {
      const int lofs = (rl + (((d * 2 + (l15 >> 3)) & 3) << 4)) * 8 + (l15 & 7);
      Yb[((size_t)(b * 128 + pa)        * 32 + h * 2 + (d >> 1)) * 512 + lofs] =
          f32_to_bf16(accA[d][r] * ivA);
      Yb[((size_t)(b * 128 + (127 - pa)) * 32 + h * 2 + (d >> 1)) * 512 + lofs] =
          f32_to_bf16(accB[d][r] * ivB);
    }
  }
}

// ---------------------------------------------------------------- launch
extern "C" void kernel_launch(void* const* d_in, const int* in_sizes, int n_in,
                              void* d_out, int out_size, void* d_ws, size_t ws_size,
                              hipStream_t stream) {
  const float* x      = (const float*)d_in[0];
  const float* w_qkv  = (const float*)d_in[1];
  const float* w_proj = (const float*)d_in[2];
  float* out = (float*)d_out;

  u16* Xb  = (u16*)d_ws;                                // blocked x
  u16* Wqt = Xb  + (size_t)MROWS * CDIM;                // blocked w_qkv^T
  u16* Wpt = Wqt + (size_t)QKVC * CDIM;                 // blocked w_proj^T
  u16* Qb  = Wpt + (size_t)CDIM * CDIM;                 // 8192*1024 (Q, pre-scaled)
  u16* Kc  = Qb  + (size_t)MROWS * CDIM;                // 64*131072 blocked K
  u16* Vc  = Kc  + (size_t)64 * 131072;                 // 64*131072 blocked V
  u16* Yb  = Vc  + (size_t)64 * 131072;                 // 8192*1024 blocked

  // casts / transposes (all blocked)
  cast_block_kernel<<<MROWS * CDIM / 8 / 256, 256, 0, stream>>>(x, Xb);
  transpose_cast_block_kernel<<<dim3(QKVC / 32, CDIM / 32), dim3(32, 8), 0, stream>>>(w_qkv, Wqt, QKVC);
  transpose_cast_block_kernel<<<dim3(CDIM / 32, CDIM / 32), dim3(32, 8), 0, stream>>>(w_proj, Wpt, CDIM);

  // qkv projection: blocked inputs, fused epilogue (Q->Qb scaled, K->Kc, V->Vc)
  gemm1_kernel<<<dim3(MROWS / 128, QKVC / 128), 256, 0, stream>>>(Xb, Wqt, Qb, Kc, Vc);

  // attention (round-19 checkpoint + setprio)
  attn_kernel<<<1024, 256, 0, stream>>>(Qb, Kc, Vc, Yb);

  // out = y @ w_proj  (blocked inputs, f32 out)
  gemm2_kernel<<<dim3(MROWS / 128, CDIM / 128), 256, 0, stream>>>(Yb, Wpt, out);
}